// Round 21
// baseline (100.395 us; speedup 1.0000x reference)
//
#include <hip/hip_runtime.h>
#include <stdint.h>

#define NB 64
#define NS 512
#define NC 256
#define NH 8
#define ND 32

typedef __attribute__((ext_vector_type(8))) short s8v;
typedef __attribute__((ext_vector_type(8))) unsigned short u8v;
typedef __attribute__((ext_vector_type(4))) float f4v;

#define LOG2E 1.4426950408889634f

static __device__ __forceinline__ uint16_t f2bf(float f) {
    uint32_t u = __builtin_bit_cast(uint32_t, f);
    u += 0x7fffu + ((u >> 16) & 1u);
    return (uint16_t)(u >> 16);
}
static __device__ __forceinline__ float bf2f(uint16_t h) {
    uint32_t u = ((uint32_t)h) << 16;
    return __builtin_bit_cast(float, u);
}
static __device__ __forceinline__ uint32_t cvtpk(float lo, float hi) {
    uint32_t r;
    asm("v_cvt_pk_bf16_f32 %0, %1, %2" : "=v"(r) : "v"(lo), "v"(hi));
    return r;
}

// permlane pair-swaps (gfx950) -- R16-verified.
#if __has_builtin(__builtin_amdgcn_permlane32_swap)
static __device__ __forceinline__ void pl32(uint32_t& a, uint32_t& b) {
    auto r = __builtin_amdgcn_permlane32_swap(a, b, false, false);
    a = r[0]; b = r[1];
}
static __device__ __forceinline__ void pl16(uint32_t& a, uint32_t& b) {
    auto r = __builtin_amdgcn_permlane16_swap(a, b, false, false);
    a = r[0]; b = r[1];
}
#else
static __device__ __forceinline__ void pl32(uint32_t& a, uint32_t& b) {
    asm volatile("v_permlane32_swap_b32 %0, %1" : "+v"(a), "+v"(b));
}
static __device__ __forceinline__ void pl16(uint32_t& a, uint32_t& b) {
    asm volatile("v_permlane16_swap_b32 %0, %1" : "+v"(a), "+v"(b));
}
#endif

// ---------------- Kernel 0: merged setup (rel table + weight converts) -------
__global__ __launch_bounds__(256) void setup_kern(const float* __restrict__ rel,
                                                  const float* __restrict__ wq,
                                                  const float* __restrict__ wp,
                                                  uint16_t* __restrict__ rel2,
                                                  uint16_t* __restrict__ wqo,
                                                  uint16_t* __restrict__ wpo) {
    const int bid = blockIdx.x;
    if (bid < 640) {
        int id = bid * 256 + threadIdx.x;          // 8 * 64 * 320 = 163840
        int h = id / 20480, rem = id % 20480;
        int dt = rem / 320, q = rem % 320;
        int li = q / 20, lj = q % 20;
        float v = (lj < 16 && dt < 63) ? rel[(((dt << 4) + li) * 16 + lj) * 8 + h] * LOG2E : 0.f;
        rel2[id] = f2bf(v);
    } else {
        int i = ((bid - 640) * 256 + threadIdx.x) * 8;
        const float* src; uint16_t* dst; int off;
        if (i < 196608) { src = wq; dst = wqo; off = i; }
        else            { src = wp; dst = wpo; off = i - 196608; }
        f4v a = *(const f4v*)(src + off);
        f4v b = *(const f4v*)(src + off + 4);
        uint4 w;
        w.x = cvtpk(a[0], a[1]); w.y = cvtpk(a[2], a[3]);
        w.z = cvtpk(b[0], b[1]); w.w = cvtpk(b[2], b[3]);
        *(uint4*)(dst + off) = w;
    }
}

// ---------------- Kernel 2: QKV GEMM, depth-2 pipeline, pad-36 LDS -----------
// Pad 40 -> 36 elems/row: 36.86 KB total -> 4 blocks/CU (was 3). Bank map
// lq*18 mod 32 is bijective over 16 lanes -> <=2-way aliasing (free).
__global__ __launch_bounds__(256) void qkv_gemm(const float* __restrict__ X,
                                                const uint16_t* __restrict__ W,
                                                const float* __restrict__ Bv,
                                                uint16_t* __restrict__ Qo,
                                                uint16_t* __restrict__ Ko,
                                                uint16_t* __restrict__ Vo) {
    __shared__ uint16_t As[2][128 * 36];
    __shared__ uint16_t Bs[2][128 * 36];
    const int tid = threadIdx.x;
    const int bn = blockIdx.y * 128;
    const int bm = blockIdx.x * 128;
    const int lane = tid & 63, wv = tid >> 6;
    const int wm = (wv >> 1) * 64, wn = (wv & 1) * 64;
    const int lq = lane & 15, g = lane >> 4;
    const int srow = tid >> 1;
    const int scol = (tid & 1) * 16;

    const float* xs = X + (size_t)(bm + srow) * 256 + scol;
    const uint16_t* wsrc = W + (size_t)(bn + srow) * 256 + scol;

    f4v acc[4][4] = {};
    f4v xr[2][4];
    u8v wr[2][2];

#define LOAD_S(set, kel)                                                    \
    do {                                                                    \
        xr[set][0] = *(const f4v*)(xs + (kel));                             \
        xr[set][1] = *(const f4v*)(xs + (kel) + 4);                         \
        xr[set][2] = *(const f4v*)(xs + (kel) + 8);                         \
        xr[set][3] = *(const f4v*)(xs + (kel) + 12);                        \
        wr[set][0] = *(const u8v*)(wsrc + (kel));                           \
        wr[set][1] = *(const u8v*)(wsrc + (kel) + 8);                       \
    } while (0)

#define STORE_S(buf, set)                                                   \
    do {                                                                    \
        uint4 q0, q1;                                                       \
        q0.x = cvtpk(xr[set][0][0], xr[set][0][1]);                         \
        q0.y = cvtpk(xr[set][0][2], xr[set][0][3]);                         \
        q0.z = cvtpk(xr[set][1][0], xr[set][1][1]);                         \
        q0.w = cvtpk(xr[set][1][2], xr[set][1][3]);                         \
        q1.x = cvtpk(xr[set][2][0], xr[set][2][1]);                         \
        q1.y = cvtpk(xr[set][2][2], xr[set][2][3]);                         \
        q1.z = cvtpk(xr[set][3][0], xr[set][3][1]);                         \
        q1.w = cvtpk(xr[set][3][2], xr[set][3][3]);                         \
        *(uint4*)(&As[buf][srow * 36 + scol])     = q0;                     \
        *(uint4*)(&As[buf][srow * 36 + scol + 8]) = q1;                     \
        *(u8v*)(&Bs[buf][srow * 36 + scol])     = wr[set][0];               \
        *(u8v*)(&Bs[buf][srow * 36 + scol + 8]) = wr[set][1];               \
    } while (0)

    LOAD_S(0, 0);
    LOAD_S(1, 32);
    STORE_S(0, 0);
    __syncthreads();

    #pragma unroll
    for (int ks = 0; ks < 8; ++ks) {
        const int cur = ks & 1;
        if (ks + 2 < 8) LOAD_S(cur, (ks + 2) * 32);
        s8v af[4], bf[4];
        #pragma unroll
        for (int i = 0; i < 4; ++i) {
            af[i] = *(const s8v*)(&As[cur][(wm + i * 16 + lq) * 36 + g * 8]);
            bf[i] = *(const s8v*)(&Bs[cur][(wn + i * 16 + lq) * 36 + g * 8]);
        }
        #pragma unroll
        for (int mt = 0; mt < 4; ++mt)
            #pragma unroll
            for (int nt = 0; nt < 4; ++nt)
                acc[mt][nt] = __builtin_amdgcn_mfma_f32_16x16x32_bf16(af[mt], bf[nt], acc[mt][nt], 0, 0, 0);
        if (ks < 7) STORE_S(cur ^ 1, (ks + 1) & 1);
        __syncthreads();
    }
#undef LOAD_S
#undef STORE_S

    const int gsel = bn >> 8;   // 0=q, 1=k, 2=v
    if (gsel == 2) {
        #pragma unroll
        for (int nt = 0; nt < 4; ++nt) {
            const int ng = bn + wn + nt * 16 + lq;
            const float bv = Bv[ng];
            const int c = ng & 255, hh = c >> 5, dd = c & 31;
            #pragma unroll
            for (int mtp = 0; mtp < 2; ++mtp) {
                f4v u = acc[mtp * 2][nt], v = acc[mtp * 2 + 1][nt];
                uint32_t A0 = cvtpk(u[0] + bv, u[1] + bv);
                uint32_t A1 = cvtpk(u[2] + bv, u[3] + bv);
                uint32_t B0 = cvtpk(v[0] + bv, v[1] + bv);
                uint32_t B1 = cvtpk(v[2] + bv, v[3] + bv);
                pl32(A0, B0); pl16(A0, B0);
                pl32(A1, B1); pl16(A1, B1);
                uint4 wq; wq.x = A0; wq.y = A1; wq.z = B0; wq.w = B1;
                const int m0 = bm + wm + mtp * 32;
                const int b = m0 >> 9;
                const int s0 = (m0 & 511) + g * 8;
                *(uint4*)(Vo + ((size_t)(b * 8 + hh) * 32 + dd) * 512 + s0) = wq;
            }
        }
    } else {
        const float scl = (gsel == 0) ? (0.35355339059327373f * LOG2E) : 1.0f;
        #pragma unroll
        for (int nt = 0; nt < 4; ++nt) {
            const int ng = bn + wn + nt * 16 + lq;
            const float bv = Bv[ng];
            const int c = ng & 255, hh = c >> 5, dd = c & 31;
            #pragma unroll
            for (int mt = 0; mt < 4; ++mt) {
                #pragma unroll
                for (int r = 0; r < 4; ++r) {
                    const int m = bm + wm + mt * 16 + g * 4 + r;
                    const int b = m >> 9, s = m & 511;
                    const uint16_t val = f2bf((acc[mt][nt][r] + bv) * scl);
                    if (gsel == 0) Qo[((size_t)(b * 8 + hh) * 512 + s) * 32 + dd] = val;
                    else           Ko[((size_t)(b * 8 + hh) * 512 + s) * 32 + dd] = val;
                }
            }
        }
    }
}

// ---------------- Kernel 3: flash attention, 39-row Rel slice ----------------
// R20-green math. ONE change: only the 39 dt rows this block can touch are
// staged (dt_rebased = wv + 31 - tj0 - i in [0,38], independent of qq), so
// LDS drops 51.2 -> 35.2 KB -> 4 blocks/CU (occupancy 47.6% -> ~63%).
__global__ __launch_bounds__(512) void attn_kern(const uint16_t* __restrict__ Q,
                                                 const uint16_t* __restrict__ K,
                                                 const uint16_t* __restrict__ V,
                                                 const uint16_t* __restrict__ REL2,
                                                 uint16_t* __restrict__ AO) {
    __shared__ uint16_t Ks[64 * 40];               // K tile: 64 t-rows x 32 d (pad 40)
    __shared__ uint16_t Vs[32 * 80];               // V^T tile: 32 d-rows x 64 t (pad 80)
    __shared__ uint16_t Rel[39 * 320];             // trimmed rel slice (24.96 KB)

    const int p = blockIdx.x;
    const int h  = p & 7;                          // XCD-pinned head
    const int qq = (p >> 3) & 3;
    const int b  = p >> 5;
    const int tid = threadIdx.x, lane = tid & 63, wv = tid >> 6;
    const int lq = lane & 15, g = lane >> 4;
    const int bh = b * 8 + h;
    const int qw = qq * 128 + wv * 16;             // window-local q base of wave

    s8v qf = *(const s8v*)(Q + ((size_t)bh * 512 + qw + lq) * 32 + g * 8);
    const uint16_t* kg = K + (size_t)bh * 16384;   // K rows t, 32 d each
    const uint16_t* vg = V + (size_t)bh * 16384;   // V^T rows d, 512 t each

    // all-ones bf16 B-operand for the denominator MFMA (R20)
    const uint32_t one2 = 0x3F803F80u;
    uint4 onesw; onesw.x = one2; onesw.y = one2; onesw.z = one2; onesw.w = one2;
    const s8v onesv = __builtin_bit_cast(s8v, onesw);

    // ---- stage the 39-row rel slice (dt in [qq*8, qq*8+38]) ----
    {
        const uint16_t* rsrc = REL2 + (size_t)h * 20480 + qq * 2560;
        #pragma unroll
        for (int it = 0; it < 4; ++it) {
            int off = it * 4096 + tid * 8;
            if (off < 12480)
                *(u8v*)(Rel + off) = *(const u8v*)(rsrc + off);
        }
    }

    // staging indices: lower half stages K, upper half stages V (line-dense)
    const bool isK = (tid < 256);
    const int t2 = tid & 255;
    const int ktrow = t2 >> 2, ktcol = (t2 & 3) * 8;     // 64 rows x 32 elems
    const int vtrow = t2 >> 3, vtcol = (t2 & 7) * 8;     // 32 rows x 64 elems
    const uint16_t* gsrc = isK ? (kg + (size_t)ktrow * 32 + ktcol)
                               : (vg + (size_t)vtrow * 512 + vtcol);
    uint16_t* ldst = isK ? (Ks + ktrow * 40 + ktcol)
                         : (Vs + vtrow * 80 + vtcol);
    const int gstep = isK ? (64 * 32) : 64;        // per-tile advance (elems)

    f4v o0 = {}, o1 = {}, ol = {};
    float mrow = -3.0e38f;

    // prologue: load tile 0 into registers
    u8v sreg = *(const u8v*)(gsrc);

    for (int tile = 0; tile < 8; ++tile) {
        const int t0 = tile * 64;

        __syncthreads();                           // prev tile's LDS reads done
        *(u8v*)(ldst) = sreg;
        __syncthreads();                           // writes visible (incl. Rel @ tile 0)

        // issue-early: next tile's global loads hide under this tile's compute
        if (tile < 7) {
            sreg = *(const u8v*)(gsrc + (size_t)(tile + 1) * gstep);
        }

        // ---- S-tile = bias (C-init from trimmed LDS rel) + K.Q^T, log2 domain
        f4v a0, a1, a2, a3;
        {
            const int tj0 = t0 >> 4;               // uniform per wave
            const uint16_t* rb = Rel + lq * 20 + g * 4;
            ushort4 z0 = *(const ushort4*)(rb + (wv + 31 - tj0 - 0) * 320);
            ushort4 z1 = *(const ushort4*)(rb + (wv + 31 - tj0 - 1) * 320);
            ushort4 z2 = *(const ushort4*)(rb + (wv + 31 - tj0 - 2) * 320);
            ushort4 z3 = *(const ushort4*)(rb + (wv + 31 - tj0 - 3) * 320);
            a0[0]=bf2f(z0.x); a0[1]=bf2f(z0.y); a0[2]=bf2f(z0.z); a0[3]=bf2f(z0.w);
            a1[0]=bf2f(z1.x); a1[1]=bf2f(z1.y); a1[2]=bf2f(z1.z); a1[3]=bf2f(z1.w);
            a2[0]=bf2f(z2.x); a2[1]=bf2f(z2.y); a2[2]=bf2f(z2.z); a2[3]=bf2f(z2.w);
            a3[0]=bf2f(z3.x); a3[1]=bf2f(z3.y); a3[2]=bf2f(z3.z); a3[3]=bf2f(z3.w);
        }
        a0 = __builtin_amdgcn_mfma_f32_16x16x32_bf16(*(const s8v*)(Ks + ( 0 + lq) * 40 + g * 8), qf, a0, 0, 0, 0);
        a1 = __builtin_amdgcn_mfma_f32_16x16x32_bf16(*(const s8v*)(Ks + (16 + lq) * 40 + g * 8), qf, a1, 0, 0, 0);
        a2 = __builtin_amdgcn_mfma_f32_16x16x32_bf16(*(const s8v*)(Ks + (32 + lq) * 40 + g * 8), qf, a2, 0, 0, 0);
        a3 = __builtin_amdgcn_mfma_f32_16x16x32_bf16(*(const s8v*)(Ks + (48 + lq) * 40 + g * 8), qf, a3, 0, 0, 0);

        // ---- row max (green) ----
        float p01 = fmaxf(fmaxf(a0[0], a0[1]), fmaxf(a0[2], a0[3]));
        float p23 = fmaxf(fmaxf(a1[0], a1[1]), fmaxf(a1[2], a1[3]));
        float p45 = fmaxf(fmaxf(a2[0], a2[1]), fmaxf(a2[2], a2[3]));
        float p67 = fmaxf(fmaxf(a3[0], a3[1]), fmaxf(a3[2], a3[3]));
        float pmax = fmaxf(fmaxf(p01, p23), fmaxf(p45, p67));
        pmax = fmaxf(pmax, __shfl_xor(pmax, 16));
        pmax = fmaxf(pmax, __shfl_xor(pmax, 32));

        // ---- online-softmax update, defer-rescale threshold 8 (green) ----
        if (!__all(pmax - mrow <= 8.0f)) {
            float mnew = fmaxf(mrow, pmax);
            float scale = __builtin_amdgcn_exp2f(mrow - mnew);
            float s0 = __shfl(scale, g * 4 + 0);
            float s1 = __shfl(scale, g * 4 + 1);
            float s2 = __shfl(scale, g * 4 + 2);
            float s3 = __shfl(scale, g * 4 + 3);
            o0[0] *= s0; o0[1] *= s1; o0[2] *= s2; o0[3] *= s3;
            o1[0] *= s0; o1[1] *= s1; o1[2] *= s2; o1[3] *= s3;
            ol[0] *= s0; ol[1] *= s1; ol[2] *= s2; ol[3] *= s3;
            mrow = mnew;
        }

        // ---- P = exp2(S - m) (l comes from the ones-column MFMA) ----
        #pragma unroll
        for (int r = 0; r < 4; ++r) {
            a0[r] = __builtin_amdgcn_exp2f(a0[r] - mrow);
            a1[r] = __builtin_amdgcn_exp2f(a1[r] - mrow);
            a2[r] = __builtin_amdgcn_exp2f(a2[r] - mrow);
            a3[r] = __builtin_amdgcn_exp2f(a3[r] - mrow);
        }

        // ---- P -> PV A-fragments via permlane swaps (R16-verified) ----
        {   // tc = 0: chunks a0,a1
            uint32_t A0 = cvtpk(a0[0], a0[1]);
            uint32_t A1 = cvtpk(a0[2], a0[3]);
            uint32_t B0 = cvtpk(a1[0], a1[1]);
            uint32_t B1 = cvtpk(a1[2], a1[3]);
            pl32(A0, B0); pl16(A0, B0);
            pl32(A1, B1); pl16(A1, B1);
            uint4 wq; wq.x = A0; wq.y = A1; wq.z = B0; wq.w = B1;
            s8v pf = __builtin_bit_cast(s8v, wq);
            s8v vf0 = *(const s8v*)(Vs + lq * 80 + g * 8);
            s8v vf2 = *(const s8v*)(Vs + (lq + 16) * 80 + g * 8);
            o0 = __builtin_amdgcn_mfma_f32_16x16x32_bf16(pf, vf0, o0, 0, 0, 0);
            o1 = __builtin_amdgcn_mfma_f32_16x16x32_bf16(pf, vf2, o1, 0, 0, 0);
            ol = __builtin_amdgcn_mfma_f32_16x16x32_bf16(pf, onesv, ol, 0, 0, 0);
        }
        {   // tc = 1: chunks a2,a3
            uint32_t A0 = cvtpk(a2[0], a2[1]);
            uint32_t A1 = cvtpk(a2[2], a2[3]);
            uint32_t B0 = cvtpk(a3[0], a3[1]);
            uint32_t B1 = cvtpk(a3[2], a3[3]);
            pl32(A0, B0); pl16(A0, B0);
            pl32(A1, B1); pl16(A1, B1);
            uint4 wq; wq.x = A0; wq.y = A1; wq.z = B0; wq.w = B1;
            s8v pf = __builtin_bit_cast(s8v, wq);
            s8v vf1 = *(const s8v*)(Vs + lq * 80 + 32 + g * 8);
            s8v vf3 = *(const s8v*)(Vs + (lq + 16) * 80 + 32 + g * 8);
            o0 = __builtin_amdgcn_mfma_f32_16x16x32_bf16(pf, vf1, o0, 0, 0, 0);
            o1 = __builtin_amdgcn_mfma_f32_16x16x32_bf16(pf, vf3, o1, 0, 0, 0);
            ol = __builtin_amdgcn_mfma_f32_16x16x32_bf16(pf, onesv, ol, 0, 0, 0);
        }
    }

    // ---- finalize: lane already holds l for row 4g+r in ol[r] (R20) ----
    #pragma unroll
    for (int r = 0; r < 4; ++r) {
        const float iv = 1.0f / ol[r];
        const int srow = b * 512 + qw + g * 4 + r;
        uint16_t* dst = AO + (size_t)srow * 256 + h * 32 + lq;
        dst[0]  = f2bf(o0[r] * iv);
        dst[16] = f2bf(o1[r] * iv);
    }
}

// ---------------- Kernel 4: output projection, depth-2 pipeline, pad-36 ------
__global__ __launch_bounds__(256) void proj_gemm(const uint16_t* __restrict__ A,
                                                 const uint16_t* __restrict__ W,
                                                 const float* __restrict__ Bv,
                                                 float* __restrict__ Out) {
    __shared__ uint16_t As[2][128 * 36];
    __shared__ uint16_t Bs[2][128 * 36];
    const int tid = threadIdx.x;
    const int bn = blockIdx.y * 128;
    const int bm = blockIdx.x * 128;
    const int lane = tid & 63, wv = tid >> 6;
    const int wm = (wv >> 1) * 64, wn = (wv & 1) * 64;
    const int lq = lane & 15, g = lane >> 4;
    const int srow = tid >> 1;
    const int scol = (tid & 1) * 16;

    const uint16_t* as = A + (size_t)(bm + srow) * 256 + scol;
    const uint16_t* wsrc = W + (size_t)(bn + srow) * 256 + scol;

    f4v acc[4][4] = {};
    u8v ar[2][2], wr[2][2];

#define LOAD_P(set, kel)                                                    \
    do {                                                                    \
        ar[set][0] = *(const u8v*)(as + (kel));                             \
        ar[set][1] = *(const u8v*)(as + (kel) + 8);                         \
        wr[set][0] = *(const u8v*)(wsrc + (kel));                           \
        wr[set][1] = *(const u8v*)(wsrc + (kel) + 8);                       \
    } while (0)

#define STORE_P(buf, set)                                                   \
    do {                                                                    \
        *(u8v*)(&As[buf][srow * 36 + scol])     = ar[set][0];               \
        *(u8v*)(&As[buf][srow * 36 + scol + 8]) = ar[set][1];               \
        *(u8v*)(&Bs[buf][srow * 36 + scol])     = wr[set][0];               \
        *(u8v*)(&Bs[buf][srow * 36 + scol + 8]) = wr[set][1];               \
    } while (0)

    LOAD_P(0, 0);
    LOAD_P(1, 32);
    STORE_P(0, 0);
    __syncthreads();

    #pragma unroll
    for (int ks = 0; ks < 8; ++ks) {
        const int cur = ks & 1;
        if (ks + 2 < 8) LOAD_P(cur, (ks + 2) * 32);
        s8v af[4], bf[4];
        #pragma unroll
        for (int i = 0; i < 4; ++i) {
            af[i] = *(const s8v*)(&As[cur][(wm + i * 16 + lq) * 36 + g * 8]);
            bf[i] = *(const s8v*)(&Bs[cur][(wn + i * 16 + lq) * 36 + g * 8]);
        }
        #pragma unroll
        for (int mt = 0; mt < 4; ++mt)
            #pragma unroll
            for (int nt = 0; nt < 4; ++nt)
                acc[mt][nt] = __builtin_amdgcn_mfma_f32_16x16x32_bf16(af[mt], bf[nt], acc[mt][nt], 0, 0, 0);
        if (ks < 7) STORE_P(cur ^ 1, (ks + 1) & 1);
        __syncthreads();
    }
#undef LOAD_P
#undef STORE_P

    #pragma unroll
    for (int nt = 0; nt < 4; ++nt) {
        const int n = bn + wn + nt * 16 + lq;
        const float bv = Bv[n];
        #pragma unroll
        for (int mt = 0; mt < 4; ++mt) {
            #pragma unroll
            for (int r = 0; r < 4; ++r) {
                const int mm = bm + wm + mt * 16 + g * 4 + r;
                Out[(size_t)mm * 256 + n] = acc[mt][nt][r] + bv;
            }
        }
    }
}

extern "C" void kernel_launch(void* const* d_in, const int* in_sizes, int n_in,
                              void* d_out, int out_size, void* d_ws, size_t ws_size,
                              hipStream_t stream) {
    const float* x      = (const float*)d_in[0];
    const float* qkv_w  = (const float*)d_in[1];
    const float* qkv_b  = (const float*)d_in[2];
    const float* proj_w = (const float*)d_in[3];
    const float* proj_b = (const float*)d_in[4];
    const float* rel    = (const float*)d_in[5];
    float* out = (float*)d_out;

    uint16_t* ws = (uint16_t*)d_ws;
    const size_t QE = (size_t)NB * NH * NS * ND;          // 8,388,608 elems
    uint16_t* Qb   = ws;                                  // 16 MiB
    uint16_t* Kb   = Qb + QE;                             // 16 MiB
    uint16_t* Vb   = Kb + QE;                             // 16 MiB
    uint16_t* Rb   = Vb + QE;                             // 16 MiB: AO
    uint16_t* REL2 = Rb + QE;                             // 8 x 20480 bf16 (320 KiB)
    uint16_t* Wqb  = REL2 + 163840;                       // 768x256 bf16 (384 KiB)
    uint16_t* Wpb  = Wqb + 196608;                        // 256x256 bf16 (128 KiB)

    setup_kern<<<768, 256, 0, stream>>>(rel, qkv_w, proj_w, REL2, Wqb, Wpb);
    qkv_gemm<<<dim3(256, 6), 256, 0, stream>>>(x, Wqb, qkv_b, Qb, Kb, Vb);
    attn_kern<<<2048, 512, 0, stream>>>(Qb, Kb, Vb, REL2, Rb);
    proj_gemm<<<dim3(256, 2), 256, 0, stream>>>(Rb, Wpb, proj_b, out);
}

// Round 22
// 98.320 us; speedup vs baseline: 1.0211x; 1.0211x over previous
//
#include <hip/hip_runtime.h>
#include <stdint.h>

#define NB 64
#define NS 512
#define NC 256
#define NH 8
#define ND 32

typedef __attribute__((ext_vector_type(8))) short s8v;
typedef __attribute__((ext_vector_type(8))) unsigned short u8v;
typedef __attribute__((ext_vector_type(4))) float f4v;

#define LOG2E 1.4426950408889634f

static __device__ __forceinline__ uint16_t f2bf(float f) {
    uint32_t u = __builtin_bit_cast(uint32_t, f);
    u += 0x7fffu + ((u >> 16) & 1u);
    return (uint16_t)(u >> 16);
}
static __device__ __forceinline__ float bf2f(uint16_t h) {
    uint32_t u = ((uint32_t)h) << 16;
    return __builtin_bit_cast(float, u);
}
static __device__ __forceinline__ uint32_t cvtpk(float lo, float hi) {
    uint32_t r;
    asm("v_cvt_pk_bf16_f32 %0, %1, %2" : "=v"(r) : "v"(lo), "v"(hi));
    return r;
}

// permlane pair-swaps (gfx950) -- R16-verified.
#if __has_builtin(__builtin_amdgcn_permlane32_swap)
static __device__ __forceinline__ void pl32(uint32_t& a, uint32_t& b) {
    auto r = __builtin_amdgcn_permlane32_swap(a, b, false, false);
    a = r[0]; b = r[1];
}
static __device__ __forceinline__ void pl16(uint32_t& a, uint32_t& b) {
    auto r = __builtin_amdgcn_permlane16_swap(a, b, false, false);
    a = r[0]; b = r[1];
}
#else
static __device__ __forceinline__ void pl32(uint32_t& a, uint32_t& b) {
    asm volatile("v_permlane32_swap_b32 %0, %1" : "+v"(a), "+v"(b));
}
static __device__ __forceinline__ void pl16(uint32_t& a, uint32_t& b) {
    asm volatile("v_permlane16_swap_b32 %0, %1" : "+v"(a), "+v"(b));
}
#endif

// ---------------- Kernel 0: merged setup (rel table + weight converts) -------
__global__ __launch_bounds__(256) void setup_kern(const float* __restrict__ rel,
                                                  const float* __restrict__ wq,
                                                  const float* __restrict__ wp,
                                                  uint16_t* __restrict__ rel2,
                                                  uint16_t* __restrict__ wqo,
                                                  uint16_t* __restrict__ wpo) {
    const int bid = blockIdx.x;
    if (bid < 640) {
        int id = bid * 256 + threadIdx.x;          // 8 * 64 * 320 = 163840
        int h = id / 20480, rem = id % 20480;
        int dt = rem / 320, q = rem % 320;
        int li = q / 20, lj = q % 20;
        float v = (lj < 16 && dt < 63) ? rel[(((dt << 4) + li) * 16 + lj) * 8 + h] * LOG2E : 0.f;
        rel2[id] = f2bf(v);
    } else {
        int i = ((bid - 640) * 256 + threadIdx.x) * 8;
        const float* src; uint16_t* dst; int off;
        if (i < 196608) { src = wq; dst = wqo; off = i; }
        else            { src = wp; dst = wpo; off = i - 196608; }
        f4v a = *(const f4v*)(src + off);
        f4v b = *(const f4v*)(src + off + 4);
        uint4 w;
        w.x = cvtpk(a[0], a[1]); w.y = cvtpk(a[2], a[3]);
        w.z = cvtpk(b[0], b[1]); w.w = cvtpk(b[2], b[3]);
        *(uint4*)(dst + off) = w;
    }
}

// ---------------- Kernel 2: QKV GEMM, depth-2 pipeline (R20-green, pad 40) ---
__global__ __launch_bounds__(256) void qkv_gemm(const float* __restrict__ X,
                                                const uint16_t* __restrict__ W,
                                                const float* __restrict__ Bv,
                                                uint16_t* __restrict__ Qo,
                                                uint16_t* __restrict__ Ko,
                                                uint16_t* __restrict__ Vo) {
    __shared__ uint16_t As[2][128 * 40];
    __shared__ uint16_t Bs[2][128 * 40];
    const int tid = threadIdx.x;
    const int bn = blockIdx.y * 128;
    const int bm = blockIdx.x * 128;
    const int lane = tid & 63, wv = tid >> 6;
    const int wm = (wv >> 1) * 64, wn = (wv & 1) * 64;
    const int lq = lane & 15, g = lane >> 4;
    const int srow = tid >> 1;
    const int scol = (tid & 1) * 16;

    const float* xs = X + (size_t)(bm + srow) * 256 + scol;
    const uint16_t* wsrc = W + (size_t)(bn + srow) * 256 + scol;

    f4v acc[4][4] = {};
    f4v xr[2][4];
    u8v wr[2][2];

#define LOAD_S(set, kel)                                                    \
    do {                                                                    \
        xr[set][0] = *(const f4v*)(xs + (kel));                             \
        xr[set][1] = *(const f4v*)(xs + (kel) + 4);                         \
        xr[set][2] = *(const f4v*)(xs + (kel) + 8);                         \
        xr[set][3] = *(const f4v*)(xs + (kel) + 12);                        \
        wr[set][0] = *(const u8v*)(wsrc + (kel));                           \
        wr[set][1] = *(const u8v*)(wsrc + (kel) + 8);                       \
    } while (0)

#define STORE_S(buf, set)                                                   \
    do {                                                                    \
        uint4 q0, q1;                                                       \
        q0.x = cvtpk(xr[set][0][0], xr[set][0][1]);                         \
        q0.y = cvtpk(xr[set][0][2], xr[set][0][3]);                         \
        q0.z = cvtpk(xr[set][1][0], xr[set][1][1]);                         \
        q0.w = cvtpk(xr[set][1][2], xr[set][1][3]);                         \
        q1.x = cvtpk(xr[set][2][0], xr[set][2][1]);                         \
        q1.y = cvtpk(xr[set][2][2], xr[set][2][3]);                         \
        q1.z = cvtpk(xr[set][3][0], xr[set][3][1]);                         \
        q1.w = cvtpk(xr[set][3][2], xr[set][3][3]);                         \
        *(uint4*)(&As[buf][srow * 40 + scol])     = q0;                     \
        *(uint4*)(&As[buf][srow * 40 + scol + 8]) = q1;                     \
        *(u8v*)(&Bs[buf][srow * 40 + scol])     = wr[set][0];               \
        *(u8v*)(&Bs[buf][srow * 40 + scol + 8]) = wr[set][1];               \
    } while (0)

    LOAD_S(0, 0);
    LOAD_S(1, 32);
    STORE_S(0, 0);
    __syncthreads();

    #pragma unroll
    for (int ks = 0; ks < 8; ++ks) {
        const int cur = ks & 1;
        if (ks + 2 < 8) LOAD_S(cur, (ks + 2) * 32);
        s8v af[4], bf[4];
        #pragma unroll
        for (int i = 0; i < 4; ++i) {
            af[i] = *(const s8v*)(&As[cur][(wm + i * 16 + lq) * 40 + g * 8]);
            bf[i] = *(const s8v*)(&Bs[cur][(wn + i * 16 + lq) * 40 + g * 8]);
        }
        #pragma unroll
        for (int mt = 0; mt < 4; ++mt)
            #pragma unroll
            for (int nt = 0; nt < 4; ++nt)
                acc[mt][nt] = __builtin_amdgcn_mfma_f32_16x16x32_bf16(af[mt], bf[nt], acc[mt][nt], 0, 0, 0);
        if (ks < 7) STORE_S(cur ^ 1, (ks + 1) & 1);
        __syncthreads();
    }
#undef LOAD_S
#undef STORE_S

    const int gsel = bn >> 8;   // 0=q, 1=k, 2=v
    if (gsel == 2) {
        #pragma unroll
        for (int nt = 0; nt < 4; ++nt) {
            const int ng = bn + wn + nt * 16 + lq;
            const float bv = Bv[ng];
            const int c = ng & 255, hh = c >> 5, dd = c & 31;
            #pragma unroll
            for (int mtp = 0; mtp < 2; ++mtp) {
                f4v u = acc[mtp * 2][nt], v = acc[mtp * 2 + 1][nt];
                uint32_t A0 = cvtpk(u[0] + bv, u[1] + bv);
                uint32_t A1 = cvtpk(u[2] + bv, u[3] + bv);
                uint32_t B0 = cvtpk(v[0] + bv, v[1] + bv);
                uint32_t B1 = cvtpk(v[2] + bv, v[3] + bv);
                pl32(A0, B0); pl16(A0, B0);
                pl32(A1, B1); pl16(A1, B1);
                uint4 wq; wq.x = A0; wq.y = A1; wq.z = B0; wq.w = B1;
                const int m0 = bm + wm + mtp * 32;
                const int b = m0 >> 9;
                const int s0 = (m0 & 511) + g * 8;
                *(uint4*)(Vo + ((size_t)(b * 8 + hh) * 32 + dd) * 512 + s0) = wq;
            }
        }
    } else {
        const float scl = (gsel == 0) ? (0.35355339059327373f * LOG2E) : 1.0f;
        #pragma unroll
        for (int nt = 0; nt < 4; ++nt) {
            const int ng = bn + wn + nt * 16 + lq;
            const float bv = Bv[ng];
            const int c = ng & 255, hh = c >> 5, dd = c & 31;
            #pragma unroll
            for (int mt = 0; mt < 4; ++mt) {
                #pragma unroll
                for (int r = 0; r < 4; ++r) {
                    const int m = bm + wm + mt * 16 + g * 4 + r;
                    const int b = m >> 9, s = m & 511;
                    const uint16_t val = f2bf((acc[mt][nt][r] + bv) * scl);
                    if (gsel == 0) Qo[((size_t)(b * 8 + hh) * 512 + s) * 32 + dd] = val;
                    else           Ko[((size_t)(b * 8 + hh) * 512 + s) * 32 + dd] = val;
                }
            }
        }
    }
}

// ---------------- Kernel 3: flash attention, double-buffered K/V -------------
// R20-green math + R21's trimmed 39-row Rel (verified). NEW: Ks/Vs are
// double-buffered (LDS 45.4 KB, still 3 blocks/CU) -> ONE barrier per tile
// instead of two; tile t+1's registers are written after tile t's compute.
__global__ __launch_bounds__(512) void attn_kern(const uint16_t* __restrict__ Q,
                                                 const uint16_t* __restrict__ K,
                                                 const uint16_t* __restrict__ V,
                                                 const uint16_t* __restrict__ REL2,
                                                 uint16_t* __restrict__ AO) {
    __shared__ uint16_t Ks[2 * 64 * 40];           // 2 x K tile (pad 40)
    __shared__ uint16_t Vs[2 * 32 * 80];           // 2 x V^T tile (pad 80)
    __shared__ uint16_t Rel[39 * 320];             // trimmed rel slice (24.96 KB)

    const int p = blockIdx.x;
    const int h  = p & 7;                          // XCD-pinned head
    const int qq = (p >> 3) & 3;
    const int b  = p >> 5;
    const int tid = threadIdx.x, lane = tid & 63, wv = tid >> 6;
    const int lq = lane & 15, g = lane >> 4;
    const int bh = b * 8 + h;
    const int qw = qq * 128 + wv * 16;             // window-local q base of wave

    s8v qf = *(const s8v*)(Q + ((size_t)bh * 512 + qw + lq) * 32 + g * 8);
    const uint16_t* kg = K + (size_t)bh * 16384;   // K rows t, 32 d each
    const uint16_t* vg = V + (size_t)bh * 16384;   // V^T rows d, 512 t each

    // all-ones bf16 B-operand for the denominator MFMA (R20)
    const uint32_t one2 = 0x3F803F80u;
    uint4 onesw; onesw.x = one2; onesw.y = one2; onesw.z = one2; onesw.w = one2;
    const s8v onesv = __builtin_bit_cast(s8v, onesw);

    // ---- stage the 39-row rel slice (dt in [qq*8, qq*8+38]) ----
    {
        const uint16_t* rsrc = REL2 + (size_t)h * 20480 + qq * 2560;
        #pragma unroll
        for (int it = 0; it < 4; ++it) {
            int off = it * 4096 + tid * 8;
            if (off < 12480)
                *(u8v*)(Rel + off) = *(const u8v*)(rsrc + off);
        }
    }

    // staging indices: lower half stages K, upper half stages V (line-dense)
    const bool isK = (tid < 256);
    const int t2 = tid & 255;
    const int ktrow = t2 >> 2, ktcol = (t2 & 3) * 8;     // 64 rows x 32 elems
    const int vtrow = t2 >> 3, vtcol = (t2 & 7) * 8;     // 32 rows x 64 elems
    const uint16_t* gsrc = isK ? (kg + (size_t)ktrow * 32 + ktcol)
                               : (vg + (size_t)vtrow * 512 + vtcol);
    uint16_t* sbase = isK ? Ks : Vs;
    const int loff = isK ? (ktrow * 40 + ktcol) : (vtrow * 80 + vtcol);
    const int gstep = isK ? (64 * 32) : 64;        // per-tile advance (elems)

    f4v o0 = {}, o1 = {}, ol = {};
    float mrow = -3.0e38f;

    // prologue: stage tile 0 into buffer 0
    u8v sreg = *(const u8v*)(gsrc);
    *(u8v*)(sbase + loff) = sreg;
    __syncthreads();                               // buf0 + Rel visible

    for (int tile = 0; tile < 8; ++tile) {
        const int t0 = tile * 64;
        const int cur = tile & 1;
        const uint16_t* ksb = Ks + cur * 2560;
        const uint16_t* vsb = Vs + cur * 2560;

        // issue-early: next tile's global loads (consumed after this compute)
        if (tile < 7) {
            sreg = *(const u8v*)(gsrc + (size_t)(tile + 1) * gstep);
        }

        // ---- S-tile = bias (C-init from trimmed LDS rel) + K.Q^T, log2 domain
        f4v a0, a1, a2, a3;
        {
            const int tj0 = t0 >> 4;               // uniform per wave
            const uint16_t* rb = Rel + lq * 20 + g * 4;
            ushort4 z0 = *(const ushort4*)(rb + (wv + 31 - tj0 - 0) * 320);
            ushort4 z1 = *(const ushort4*)(rb + (wv + 31 - tj0 - 1) * 320);
            ushort4 z2 = *(const ushort4*)(rb + (wv + 31 - tj0 - 2) * 320);
            ushort4 z3 = *(const ushort4*)(rb + (wv + 31 - tj0 - 3) * 320);
            a0[0]=bf2f(z0.x); a0[1]=bf2f(z0.y); a0[2]=bf2f(z0.z); a0[3]=bf2f(z0.w);
            a1[0]=bf2f(z1.x); a1[1]=bf2f(z1.y); a1[2]=bf2f(z1.z); a1[3]=bf2f(z1.w);
            a2[0]=bf2f(z2.x); a2[1]=bf2f(z2.y); a2[2]=bf2f(z2.z); a2[3]=bf2f(z2.w);
            a3[0]=bf2f(z3.x); a3[1]=bf2f(z3.y); a3[2]=bf2f(z3.z); a3[3]=bf2f(z3.w);
        }
        a0 = __builtin_amdgcn_mfma_f32_16x16x32_bf16(*(const s8v*)(ksb + ( 0 + lq) * 40 + g * 8), qf, a0, 0, 0, 0);
        a1 = __builtin_amdgcn_mfma_f32_16x16x32_bf16(*(const s8v*)(ksb + (16 + lq) * 40 + g * 8), qf, a1, 0, 0, 0);
        a2 = __builtin_amdgcn_mfma_f32_16x16x32_bf16(*(const s8v*)(ksb + (32 + lq) * 40 + g * 8), qf, a2, 0, 0, 0);
        a3 = __builtin_amdgcn_mfma_f32_16x16x32_bf16(*(const s8v*)(ksb + (48 + lq) * 40 + g * 8), qf, a3, 0, 0, 0);

        // ---- row max (green) ----
        float p01 = fmaxf(fmaxf(a0[0], a0[1]), fmaxf(a0[2], a0[3]));
        float p23 = fmaxf(fmaxf(a1[0], a1[1]), fmaxf(a1[2], a1[3]));
        float p45 = fmaxf(fmaxf(a2[0], a2[1]), fmaxf(a2[2], a2[3]));
        float p67 = fmaxf(fmaxf(a3[0], a3[1]), fmaxf(a3[2], a3[3]));
        float pmax = fmaxf(fmaxf(p01, p23), fmaxf(p45, p67));
        pmax = fmaxf(pmax, __shfl_xor(pmax, 16));
        pmax = fmaxf(pmax, __shfl_xor(pmax, 32));

        // ---- online-softmax update, defer-rescale threshold 8 (green) ----
        if (!__all(pmax - mrow <= 8.0f)) {
            float mnew = fmaxf(mrow, pmax);
            float scale = __builtin_amdgcn_exp2f(mrow - mnew);
            float s0 = __shfl(scale, g * 4 + 0);
            float s1 = __shfl(scale, g * 4 + 1);
            float s2 = __shfl(scale, g * 4 + 2);
            float s3 = __shfl(scale, g * 4 + 3);
            o0[0] *= s0; o0[1] *= s1; o0[2] *= s2; o0[3] *= s3;
            o1[0] *= s0; o1[1] *= s1; o1[2] *= s2; o1[3] *= s3;
            ol[0] *= s0; ol[1] *= s1; ol[2] *= s2; ol[3] *= s3;
            mrow = mnew;
        }

        // ---- P = exp2(S - m) (l comes from the ones-column MFMA) ----
        #pragma unroll
        for (int r = 0; r < 4; ++r) {
            a0[r] = __builtin_amdgcn_exp2f(a0[r] - mrow);
            a1[r] = __builtin_amdgcn_exp2f(a1[r] - mrow);
            a2[r] = __builtin_amdgcn_exp2f(a2[r] - mrow);
            a3[r] = __builtin_amdgcn_exp2f(a3[r] - mrow);
        }

        // ---- P -> PV A-fragments via permlane swaps (R16-verified) ----
        {   // tc = 0: chunks a0,a1
            uint32_t A0 = cvtpk(a0[0], a0[1]);
            uint32_t A1 = cvtpk(a0[2], a0[3]);
            uint32_t B0 = cvtpk(a1[0], a1[1]);
            uint32_t B1 = cvtpk(a1[2], a1[3]);
            pl32(A0, B0); pl16(A0, B0);
            pl32(A1, B1); pl16(A1, B1);
            uint4 wq; wq.x = A0; wq.y = A1; wq.z = B0; wq.w = B1;
            s8v pf = __builtin_bit_cast(s8v, wq);
            s8v vf0 = *(const s8v*)(vsb + lq * 80 + g * 8);
            s8v vf2 = *(const s8v*)(vsb + (lq + 16) * 80 + g * 8);
            o0 = __builtin_amdgcn_mfma_f32_16x16x32_bf16(pf, vf0, o0, 0, 0, 0);
            o1 = __builtin_amdgcn_mfma_f32_16x16x32_bf16(pf, vf2, o1, 0, 0, 0);
            ol = __builtin_amdgcn_mfma_f32_16x16x32_bf16(pf, onesv, ol, 0, 0, 0);
        }
        {   // tc = 1: chunks a2,a3
            uint32_t A0 = cvtpk(a2[0], a2[1]);
            uint32_t A1 = cvtpk(a2[2], a2[3]);
            uint32_t B0 = cvtpk(a3[0], a3[1]);
            uint32_t B1 = cvtpk(a3[2], a3[3]);
            pl32(A0, B0); pl16(A0, B0);
            pl32(A1, B1); pl16(A1, B1);
            uint4 wq; wq.x = A0; wq.y = A1; wq.z = B0; wq.w = B1;
            s8v pf = __builtin_bit_cast(s8v, wq);
            s8v vf1 = *(const s8v*)(vsb + lq * 80 + 32 + g * 8);
            s8v vf3 = *(const s8v*)(vsb + (lq + 16) * 80 + 32 + g * 8);
            o0 = __builtin_amdgcn_mfma_f32_16x16x32_bf16(pf, vf1, o0, 0, 0, 0);
            o1 = __builtin_amdgcn_mfma_f32_16x16x32_bf16(pf, vf3, o1, 0, 0, 0);
            ol = __builtin_amdgcn_mfma_f32_16x16x32_bf16(pf, onesv, ol, 0, 0, 0);
        }

        // ---- stage tile t+1 into the other buffer (readers start next tile)
        if (tile < 7) {
            *(u8v*)(sbase + (cur ^ 1) * 2560 + loff) = sreg;
        }
        __syncthreads();                           // one barrier per tile
    }

    // ---- finalize: lane already holds l for row 4g+r in ol[r] (R20) ----
    #pragma unroll
    for (int r = 0; r < 4; ++r) {
        const float iv = 1.0f / ol[r];
        const int srow = b * 512 + qw + g * 4 + r;
        uint16_t* dst = AO + (size_t)srow * 256 + h * 32 + lq;
        dst[0]  = f2bf(o0[r] * iv);
        dst[16] = f2bf(o1[r] * iv);
    }
}

// ---------------- Kernel 4: output projection, depth-2 pipeline (R20, pad 40)
__global__ __launch_bounds__(256) void proj_gemm(const uint16_t* __restrict__ A,
                                                 const uint16_t* __restrict__ W,
                                                 const float* __restrict__ Bv,
                                                 float* __restrict__ Out) {
    __shared__ uint16_t As[2][128 * 40];
    __shared__ uint16_t Bs[2][128 * 40];
    const int tid = threadIdx.x;
    const int bn = blockIdx.y * 128;
    const int bm = blockIdx.x * 128;
    const int lane = tid & 63, wv = tid >> 6;
    const int wm = (wv >> 1) * 64, wn = (wv & 1) * 64;
    const int lq = lane & 15, g = lane >> 4;
    const int srow = tid >> 1;
    const int scol = (tid & 1) * 16;

    const uint16_t* as = A + (size_t)(bm + srow) * 256 + scol;
    const uint16_t* wsrc = W + (size_t)(bn + srow) * 256 + scol;

    f4v acc[4][4] = {};
    u8v ar[2][2], wr[2][2];

#define LOAD_P(set, kel)                                                    \
    do {                                                                    \
        ar[set][0] = *(const u8v*)(as + (kel));                             \
        ar[set][1] = *(const u8v*)(as + (kel) + 8);                         \
        wr[set][0] = *(const u8v*)(wsrc + (kel));                           \
        wr[set][1] = *(const u8v*)(wsrc + (kel) + 8);                       \
    } while (0)

#define STORE_P(buf, set)                                                   \
    do {                                                                    \
        *(u8v*)(&As[buf][srow * 40 + scol])     = ar[set][0];               \
        *(u8v*)(&As[buf][srow * 40 + scol + 8]) = ar[set][1];               \
        *(u8v*)(&Bs[buf][srow * 40 + scol])     = wr[set][0];               \
        *(u8v*)(&Bs[buf][srow * 40 + scol + 8]) = wr[set][1];               \
    } while (0)

    LOAD_P(0, 0);
    LOAD_P(1, 32);
    STORE_P(0, 0);
    __syncthreads();

    #pragma unroll
    for (int ks = 0; ks < 8; ++ks) {
        const int cur = ks & 1;
        if (ks + 2 < 8) LOAD_P(cur, (ks + 2) * 32);
        s8v af[4], bf[4];
        #pragma unroll
        for (int i = 0; i < 4; ++i) {
            af[i] = *(const s8v*)(&As[cur][(wm + i * 16 + lq) * 40 + g * 8]);
            bf[i] = *(const s8v*)(&Bs[cur][(wn + i * 16 + lq) * 40 + g * 8]);
        }
        #pragma unroll
        for (int mt = 0; mt < 4; ++mt)
            #pragma unroll
            for (int nt = 0; nt < 4; ++nt)
                acc[mt][nt] = __builtin_amdgcn_mfma_f32_16x16x32_bf16(af[mt], bf[nt], acc[mt][nt], 0, 0, 0);
        if (ks < 7) STORE_P(cur ^ 1, (ks + 1) & 1);
        __syncthreads();
    }
#undef LOAD_P
#undef STORE_P

    #pragma unroll
    for (int nt = 0; nt < 4; ++nt) {
        const int n = bn + wn + nt * 16 + lq;
        const float bv = Bv[n];
        #pragma unroll
        for (int mt = 0; mt < 4; ++mt) {
            #pragma unroll
            for (int r = 0; r < 4; ++r) {
                const int mm = bm + wm + mt * 16 + g * 4 + r;
                Out[(size_t)mm * 256 + n] = acc[mt][nt][r] + bv;
            }
        }
    }
}

extern "C" void kernel_launch(void* const* d_in, const int* in_sizes, int n_in,
                              void* d_out, int out_size, void* d_ws, size_t ws_size,
                              hipStream_t stream) {
    const float* x      = (const float*)d_in[0];
    const float* qkv_w  = (const float*)d_in[1];
    const float* qkv_b  = (const float*)d_in[2];
    const float* proj_w = (const float*)d_in[3];
    const float* proj_b = (const float*)d_in[4];
    const float* rel    = (const float*)d_in[5];
    float* out = (float*)d_out;

    uint16_t* ws = (uint16_t*)d_ws;
    const size_t QE = (size_t)NB * NH * NS * ND;          // 8,388,608 elems
    uint16_t* Qb   = ws;                                  // 16 MiB
    uint16_t* Kb   = Qb + QE;                             // 16 MiB
    uint16_t* Vb   = Kb + QE;                             // 16 MiB
    uint16_t* Rb   = Vb + QE;                             // 16 MiB: AO
    uint16_t* REL2 = Rb + QE;                             // 8 x 20480 bf16 (320 KiB)
    uint16_t* Wqb  = REL2 + 163840;                       // 768x256 bf16 (384 KiB)
    uint16_t* Wpb  = Wqb + 196608;                        // 256x256 bf16 (128 KiB)

    setup_kern<<<768, 256, 0, stream>>>(rel, qkv_w, proj_w, REL2, Wqb, Wpb);
    qkv_gemm<<<dim3(256, 6), 256, 0, stream>>>(x, Wqb, qkv_b, Qb, Kb, Vb);
    attn_kern<<<2048, 512, 0, stream>>>(Qb, Kb, Vb, REL2, Rb);
    proj_gemm<<<dim3(256, 2), 256, 0, stream>>>(Rb, Wpb, proj_b, out);
}

// Round 23
// 98.066 us; speedup vs baseline: 1.0237x; 1.0026x over previous
//
#include <hip/hip_runtime.h>
#include <stdint.h>

#define NB 64
#define NS 512
#define NC 256
#define NH 8
#define ND 32

typedef __attribute__((ext_vector_type(8))) short s8v;
typedef __attribute__((ext_vector_type(8))) unsigned short u8v;
typedef __attribute__((ext_vector_type(4))) float f4v;

#define LOG2E 1.4426950408889634f

static __device__ __forceinline__ uint16_t f2bf(float f) {
    uint32_t u = __builtin_bit_cast(uint32_t, f);
    u += 0x7fffu + ((u >> 16) & 1u);
    return (uint16_t)(u >> 16);
}
static __device__ __forceinline__ float bf2f(uint16_t h) {
    uint32_t u = ((uint32_t)h) << 16;
    return __builtin_bit_cast(float, u);
}
static __device__ __forceinline__ uint32_t cvtpk(float lo, float hi) {
    uint32_t r;
    asm("v_cvt_pk_bf16_f32 %0, %1, %2" : "=v"(r) : "v"(lo), "v"(hi));
    return r;
}

// permlane pair-swaps (gfx950) -- R16-verified.
#if __has_builtin(__builtin_amdgcn_permlane32_swap)
static __device__ __forceinline__ void pl32(uint32_t& a, uint32_t& b) {
    auto r = __builtin_amdgcn_permlane32_swap(a, b, false, false);
    a = r[0]; b = r[1];
}
static __device__ __forceinline__ void pl16(uint32_t& a, uint32_t& b) {
    auto r = __builtin_amdgcn_permlane16_swap(a, b, false, false);
    a = r[0]; b = r[1];
}
#else
static __device__ __forceinline__ void pl32(uint32_t& a, uint32_t& b) {
    asm volatile("v_permlane32_swap_b32 %0, %1" : "+v"(a), "+v"(b));
}
static __device__ __forceinline__ void pl16(uint32_t& a, uint32_t& b) {
    asm volatile("v_permlane16_swap_b32 %0, %1" : "+v"(a), "+v"(b));
}
#endif

// ---------------- Kernel 0: merged setup (rel table + weight converts) -------
__global__ __launch_bounds__(256) void setup_kern(const float* __restrict__ rel,
                                                  const float* __restrict__ wq,
                                                  const float* __restrict__ wp,
                                                  uint16_t* __restrict__ rel2,
                                                  uint16_t* __restrict__ wqo,
                                                  uint16_t* __restrict__ wpo) {
    const int bid = blockIdx.x;
    if (bid < 640) {
        int id = bid * 256 + threadIdx.x;          // 8 * 64 * 320 = 163840
        int h = id / 20480, rem = id % 20480;
        int dt = rem / 320, q = rem % 320;
        int li = q / 20, lj = q % 20;
        float v = (lj < 16 && dt < 63) ? rel[(((dt << 4) + li) * 16 + lj) * 8 + h] * LOG2E : 0.f;
        rel2[id] = f2bf(v);
    } else {
        int i = ((bid - 640) * 256 + threadIdx.x) * 8;
        const float* src; uint16_t* dst; int off;
        if (i < 196608) { src = wq; dst = wqo; off = i; }
        else            { src = wp; dst = wpo; off = i - 196608; }
        f4v a = *(const f4v*)(src + off);
        f4v b = *(const f4v*)(src + off + 4);
        uint4 w;
        w.x = cvtpk(a[0], a[1]); w.y = cvtpk(a[2], a[3]);
        w.z = cvtpk(b[0], b[1]); w.w = cvtpk(b[2], b[3]);
        *(uint4*)(dst + off) = w;
    }
}

// ---------------- Kernel 2: QKV GEMM, BM=64 tiles, depth-2 pipeline ----------
// Half-height M-tiles: LDS 30.7 KB -> 5 blocks/CU resident (was 3 @ 22.6% occ).
// Grid dim3(512,6): 512 % 8 == 0 keeps all 6 bn-passes of a bm on one XCD.
// Wave tile 32x64 (acc[2][4]). Same depth-2 register pipeline + V permlane
// epilogue (single pair) as R22-green.
__global__ __launch_bounds__(256) void qkv_gemm(const float* __restrict__ X,
                                                const uint16_t* __restrict__ W,
                                                const float* __restrict__ Bv,
                                                uint16_t* __restrict__ Qo,
                                                uint16_t* __restrict__ Ko,
                                                uint16_t* __restrict__ Vo) {
    __shared__ uint16_t As[2][64 * 40];
    __shared__ uint16_t Bs[2][128 * 40];
    const int tid = threadIdx.x;
    const int bn = blockIdx.y * 128;
    const int bm = blockIdx.x * 64;
    const int lane = tid & 63, wv = tid >> 6;
    const int wm = (wv >> 1) * 32, wn = (wv & 1) * 64;
    const int lq = lane & 15, g = lane >> 4;
    const int arow = tid >> 2, acol = (tid & 3) * 8;     // A: 64 rows x 32, 8/thr
    const int srow = tid >> 1, scol = (tid & 1) * 16;    // B: 128 rows x 32, 16/thr

    const float* xs = X + (size_t)(bm + arow) * 256 + acol;
    const uint16_t* wsrc = W + (size_t)(bn + srow) * 256 + scol;

    f4v acc[2][4] = {};
    f4v xr[2][2];
    u8v wr[2][2];

#define LOAD_S(set, kel)                                                    \
    do {                                                                    \
        xr[set][0] = *(const f4v*)(xs + (kel));                             \
        xr[set][1] = *(const f4v*)(xs + (kel) + 4);                         \
        wr[set][0] = *(const u8v*)(wsrc + (kel));                           \
        wr[set][1] = *(const u8v*)(wsrc + (kel) + 8);                       \
    } while (0)

#define STORE_S(buf, set)                                                   \
    do {                                                                    \
        uint4 q0;                                                           \
        q0.x = cvtpk(xr[set][0][0], xr[set][0][1]);                         \
        q0.y = cvtpk(xr[set][0][2], xr[set][0][3]);                         \
        q0.z = cvtpk(xr[set][1][0], xr[set][1][1]);                         \
        q0.w = cvtpk(xr[set][1][2], xr[set][1][3]);                         \
        *(uint4*)(&As[buf][arow * 40 + acol]) = q0;                         \
        *(u8v*)(&Bs[buf][srow * 40 + scol])     = wr[set][0];               \
        *(u8v*)(&Bs[buf][srow * 40 + scol + 8]) = wr[set][1];               \
    } while (0)

    LOAD_S(0, 0);
    LOAD_S(1, 32);
    STORE_S(0, 0);
    __syncthreads();

    #pragma unroll
    for (int ks = 0; ks < 8; ++ks) {
        const int cur = ks & 1;
        if (ks + 2 < 8) LOAD_S(cur, (ks + 2) * 32);
        s8v af[2], bf[4];
        #pragma unroll
        for (int i = 0; i < 2; ++i)
            af[i] = *(const s8v*)(&As[cur][(wm + i * 16 + lq) * 40 + g * 8]);
        #pragma unroll
        for (int i = 0; i < 4; ++i)
            bf[i] = *(const s8v*)(&Bs[cur][(wn + i * 16 + lq) * 40 + g * 8]);
        #pragma unroll
        for (int mt = 0; mt < 2; ++mt)
            #pragma unroll
            for (int nt = 0; nt < 4; ++nt)
                acc[mt][nt] = __builtin_amdgcn_mfma_f32_16x16x32_bf16(af[mt], bf[nt], acc[mt][nt], 0, 0, 0);
        if (ks < 7) STORE_S(cur ^ 1, (ks + 1) & 1);
        __syncthreads();
    }
#undef LOAD_S
#undef STORE_S

    const int gsel = bn >> 8;   // 0=q, 1=k, 2=v
    if (gsel == 2) {
        // ---- V: permlane transform -> 8 consecutive s per lane, 16B store
        #pragma unroll
        for (int nt = 0; nt < 4; ++nt) {
            const int ng = bn + wn + nt * 16 + lq;
            const float bv = Bv[ng];
            const int c = ng & 255, hh = c >> 5, dd = c & 31;
            f4v u = acc[0][nt], v = acc[1][nt];
            uint32_t A0 = cvtpk(u[0] + bv, u[1] + bv);
            uint32_t A1 = cvtpk(u[2] + bv, u[3] + bv);
            uint32_t B0 = cvtpk(v[0] + bv, v[1] + bv);
            uint32_t B1 = cvtpk(v[2] + bv, v[3] + bv);
            pl32(A0, B0); pl16(A0, B0);
            pl32(A1, B1); pl16(A1, B1);
            uint4 wq; wq.x = A0; wq.y = A1; wq.z = B0; wq.w = B1;
            const int m0 = bm + wm;
            const int b = m0 >> 9;
            const int s0 = (m0 & 511) + g * 8;
            *(uint4*)(Vo + ((size_t)(b * 8 + hh) * 32 + dd) * 512 + s0) = wq;
        }
    } else {
        const float scl = (gsel == 0) ? (0.35355339059327373f * LOG2E) : 1.0f;
        #pragma unroll
        for (int nt = 0; nt < 4; ++nt) {
            const int ng = bn + wn + nt * 16 + lq;
            const float bv = Bv[ng];
            const int c = ng & 255, hh = c >> 5, dd = c & 31;
            #pragma unroll
            for (int mt = 0; mt < 2; ++mt) {
                #pragma unroll
                for (int r = 0; r < 4; ++r) {
                    const int m = bm + wm + mt * 16 + g * 4 + r;
                    const int b = m >> 9, s = m & 511;
                    const uint16_t val = f2bf((acc[mt][nt][r] + bv) * scl);
                    if (gsel == 0) Qo[((size_t)(b * 8 + hh) * 512 + s) * 32 + dd] = val;
                    else           Ko[((size_t)(b * 8 + hh) * 512 + s) * 32 + dd] = val;
                }
            }
        }
    }
}

// ---------------- Kernel 3: flash attention (R22-green, dbuf K/V) ------------
__global__ __launch_bounds__(512) void attn_kern(const uint16_t* __restrict__ Q,
                                                 const uint16_t* __restrict__ K,
                                                 const uint16_t* __restrict__ V,
                                                 const uint16_t* __restrict__ REL2,
                                                 uint16_t* __restrict__ AO) {
    __shared__ uint16_t Ks[2 * 64 * 40];           // 2 x K tile (pad 40)
    __shared__ uint16_t Vs[2 * 32 * 80];           // 2 x V^T tile (pad 80)
    __shared__ uint16_t Rel[39 * 320];             // trimmed rel slice (24.96 KB)

    const int p = blockIdx.x;
    const int h  = p & 7;                          // XCD-pinned head
    const int qq = (p >> 3) & 3;
    const int b  = p >> 5;
    const int tid = threadIdx.x, lane = tid & 63, wv = tid >> 6;
    const int lq = lane & 15, g = lane >> 4;
    const int bh = b * 8 + h;
    const int qw = qq * 128 + wv * 16;             // window-local q base of wave

    s8v qf = *(const s8v*)(Q + ((size_t)bh * 512 + qw + lq) * 32 + g * 8);
    const uint16_t* kg = K + (size_t)bh * 16384;   // K rows t, 32 d each
    const uint16_t* vg = V + (size_t)bh * 16384;   // V^T rows d, 512 t each

    // all-ones bf16 B-operand for the denominator MFMA (R20)
    const uint32_t one2 = 0x3F803F80u;
    uint4 onesw; onesw.x = one2; onesw.y = one2; onesw.z = one2; onesw.w = one2;
    const s8v onesv = __builtin_bit_cast(s8v, onesw);

    // ---- stage the 39-row rel slice (dt in [qq*8, qq*8+38]) ----
    {
        const uint16_t* rsrc = REL2 + (size_t)h * 20480 + qq * 2560;
        #pragma unroll
        for (int it = 0; it < 4; ++it) {
            int off = it * 4096 + tid * 8;
            if (off < 12480)
                *(u8v*)(Rel + off) = *(const u8v*)(rsrc + off);
        }
    }

    // staging indices: lower half stages K, upper half stages V (line-dense)
    const bool isK = (tid < 256);
    const int t2 = tid & 255;
    const int ktrow = t2 >> 2, ktcol = (t2 & 3) * 8;     // 64 rows x 32 elems
    const int vtrow = t2 >> 3, vtcol = (t2 & 7) * 8;     // 32 rows x 64 elems
    const uint16_t* gsrc = isK ? (kg + (size_t)ktrow * 32 + ktcol)
                               : (vg + (size_t)vtrow * 512 + vtcol);
    uint16_t* sbase = isK ? Ks : Vs;
    const int loff = isK ? (ktrow * 40 + ktcol) : (vtrow * 80 + vtcol);
    const int gstep = isK ? (64 * 32) : 64;        // per-tile advance (elems)

    f4v o0 = {}, o1 = {}, ol = {};
    float mrow = -3.0e38f;

    // prologue: stage tile 0 into buffer 0
    u8v sreg = *(const u8v*)(gsrc);
    *(u8v*)(sbase + loff) = sreg;
    __syncthreads();                               // buf0 + Rel visible

    for (int tile = 0; tile < 8; ++tile) {
        const int t0 = tile * 64;
        const int cur = tile & 1;
        const uint16_t* ksb = Ks + cur * 2560;
        const uint16_t* vsb = Vs + cur * 2560;

        // issue-early: next tile's global loads (consumed after this compute)
        if (tile < 7) {
            sreg = *(const u8v*)(gsrc + (size_t)(tile + 1) * gstep);
        }

        // ---- S-tile = bias (C-init from trimmed LDS rel) + K.Q^T, log2 domain
        f4v a0, a1, a2, a3;
        {
            const int tj0 = t0 >> 4;               // uniform per wave
            const uint16_t* rb = Rel + lq * 20 + g * 4;
            ushort4 z0 = *(const ushort4*)(rb + (wv + 31 - tj0 - 0) * 320);
            ushort4 z1 = *(const ushort4*)(rb + (wv + 31 - tj0 - 1) * 320);
            ushort4 z2 = *(const ushort4*)(rb + (wv + 31 - tj0 - 2) * 320);
            ushort4 z3 = *(const ushort4*)(rb + (wv + 31 - tj0 - 3) * 320);
            a0[0]=bf2f(z0.x); a0[1]=bf2f(z0.y); a0[2]=bf2f(z0.z); a0[3]=bf2f(z0.w);
            a1[0]=bf2f(z1.x); a1[1]=bf2f(z1.y); a1[2]=bf2f(z1.z); a1[3]=bf2f(z1.w);
            a2[0]=bf2f(z2.x); a2[1]=bf2f(z2.y); a2[2]=bf2f(z2.z); a2[3]=bf2f(z2.w);
            a3[0]=bf2f(z3.x); a3[1]=bf2f(z3.y); a3[2]=bf2f(z3.z); a3[3]=bf2f(z3.w);
        }
        a0 = __builtin_amdgcn_mfma_f32_16x16x32_bf16(*(const s8v*)(ksb + ( 0 + lq) * 40 + g * 8), qf, a0, 0, 0, 0);
        a1 = __builtin_amdgcn_mfma_f32_16x16x32_bf16(*(const s8v*)(ksb + (16 + lq) * 40 + g * 8), qf, a1, 0, 0, 0);
        a2 = __builtin_amdgcn_mfma_f32_16x16x32_bf16(*(const s8v*)(ksb + (32 + lq) * 40 + g * 8), qf, a2, 0, 0, 0);
        a3 = __builtin_amdgcn_mfma_f32_16x16x32_bf16(*(const s8v*)(ksb + (48 + lq) * 40 + g * 8), qf, a3, 0, 0, 0);

        // ---- row max (green) ----
        float p01 = fmaxf(fmaxf(a0[0], a0[1]), fmaxf(a0[2], a0[3]));
        float p23 = fmaxf(fmaxf(a1[0], a1[1]), fmaxf(a1[2], a1[3]));
        float p45 = fmaxf(fmaxf(a2[0], a2[1]), fmaxf(a2[2], a2[3]));
        float p67 = fmaxf(fmaxf(a3[0], a3[1]), fmaxf(a3[2], a3[3]));
        float pmax = fmaxf(fmaxf(p01, p23), fmaxf(p45, p67));
        pmax = fmaxf(pmax, __shfl_xor(pmax, 16));
        pmax = fmaxf(pmax, __shfl_xor(pmax, 32));

        // ---- online-softmax update, defer-rescale threshold 8 (green) ----
        if (!__all(pmax - mrow <= 8.0f)) {
            float mnew = fmaxf(mrow, pmax);
            float scale = __builtin_amdgcn_exp2f(mrow - mnew);
            float s0 = __shfl(scale, g * 4 + 0);
            float s1 = __shfl(scale, g * 4 + 1);
            float s2 = __shfl(scale, g * 4 + 2);
            float s3 = __shfl(scale, g * 4 + 3);
            o0[0] *= s0; o0[1] *= s1; o0[2] *= s2; o0[3] *= s3;
            o1[0] *= s0; o1[1] *= s1; o1[2] *= s2; o1[3] *= s3;
            ol[0] *= s0; ol[1] *= s1; ol[2] *= s2; ol[3] *= s3;
            mrow = mnew;
        }

        // ---- P = exp2(S - m) (l comes from the ones-column MFMA) ----
        #pragma unroll
        for (int r = 0; r < 4; ++r) {
            a0[r] = __builtin_amdgcn_exp2f(a0[r] - mrow);
            a1[r] = __builtin_amdgcn_exp2f(a1[r] - mrow);
            a2[r] = __builtin_amdgcn_exp2f(a2[r] - mrow);
            a3[r] = __builtin_amdgcn_exp2f(a3[r] - mrow);
        }

        // ---- P -> PV A-fragments via permlane swaps (R16-verified) ----
        {   // tc = 0: chunks a0,a1
            uint32_t A0 = cvtpk(a0[0], a0[1]);
            uint32_t A1 = cvtpk(a0[2], a0[3]);
            uint32_t B0 = cvtpk(a1[0], a1[1]);
            uint32_t B1 = cvtpk(a1[2], a1[3]);
            pl32(A0, B0); pl16(A0, B0);
            pl32(A1, B1); pl16(A1, B1);
            uint4 wq; wq.x = A0; wq.y = A1; wq.z = B0; wq.w = B1;
            s8v pf = __builtin_bit_cast(s8v, wq);
            s8v vf0 = *(const s8v*)(vsb + lq * 80 + g * 8);
            s8v vf2 = *(const s8v*)(vsb + (lq + 16) * 80 + g * 8);
            o0 = __builtin_amdgcn_mfma_f32_16x16x32_bf16(pf, vf0, o0, 0, 0, 0);
            o1 = __builtin_amdgcn_mfma_f32_16x16x32_bf16(pf, vf2, o1, 0, 0, 0);
            ol = __builtin_amdgcn_mfma_f32_16x16x32_bf16(pf, onesv, ol, 0, 0, 0);
        }
        {   // tc = 1: chunks a2,a3
            uint32_t A0 = cvtpk(a2[0], a2[1]);
            uint32_t A1 = cvtpk(a2[2], a2[3]);
            uint32_t B0 = cvtpk(a3[0], a3[1]);
            uint32_t B1 = cvtpk(a3[2], a3[3]);
            pl32(A0, B0); pl16(A0, B0);
            pl32(A1, B1); pl16(A1, B1);
            uint4 wq; wq.x = A0; wq.y = A1; wq.z = B0; wq.w = B1;
            s8v pf = __builtin_bit_cast(s8v, wq);
            s8v vf1 = *(const s8v*)(vsb + lq * 80 + 32 + g * 8);
            s8v vf3 = *(const s8v*)(vsb + (lq + 16) * 80 + 32 + g * 8);
            o0 = __builtin_amdgcn_mfma_f32_16x16x32_bf16(pf, vf1, o0, 0, 0, 0);
            o1 = __builtin_amdgcn_mfma_f32_16x16x32_bf16(pf, vf3, o1, 0, 0, 0);
            ol = __builtin_amdgcn_mfma_f32_16x16x32_bf16(pf, onesv, ol, 0, 0, 0);
        }

        // ---- stage tile t+1 into the other buffer (readers start next tile)
        if (tile < 7) {
            *(u8v*)(sbase + (cur ^ 1) * 2560 + loff) = sreg;
        }
        __syncthreads();                           // one barrier per tile
    }

    // ---- finalize: lane already holds l for row 4g+r in ol[r] (R20) ----
    #pragma unroll
    for (int r = 0; r < 4; ++r) {
        const float iv = 1.0f / ol[r];
        const int srow = b * 512 + qw + g * 4 + r;
        uint16_t* dst = AO + (size_t)srow * 256 + h * 32 + lq;
        dst[0]  = f2bf(o0[r] * iv);
        dst[16] = f2bf(o1[r] * iv);
    }
}

// ---------------- Kernel 4: output projection, depth-2 pipeline (R20, pad 40)
__global__ __launch_bounds__(256) void proj_gemm(const uint16_t* __restrict__ A,
                                                 const uint16_t* __restrict__ W,
                                                 const float* __restrict__ Bv,
                                                 float* __restrict__ Out) {
    __shared__ uint16_t As[2][128 * 40];
    __shared__ uint16_t Bs[2][128 * 40];
    const int tid = threadIdx.x;
    const int bn = blockIdx.y * 128;
    const int bm = blockIdx.x * 128;
    const int lane = tid & 63, wv = tid >> 6;
    const int wm = (wv >> 1) * 64, wn = (wv & 1) * 64;
    const int lq = lane & 15, g = lane >> 4;
    const int srow = tid >> 1;
    const int scol = (tid & 1) * 16;

    const uint16_t* as = A + (size_t)(bm + srow) * 256 + scol;
    const uint16_t* wsrc = W + (size_t)(bn + srow) * 256 + scol;

    f4v acc[4][4] = {};
    u8v ar[2][2], wr[2][2];

#define LOAD_P(set, kel)                                                    \
    do {                                                                    \
        ar[set][0] = *(const u8v*)(as + (kel));                             \
        ar[set][1] = *(const u8v*)(as + (kel) + 8);                         \
        wr[set][0] = *(const u8v*)(wsrc + (kel));                           \
        wr[set][1] = *(const u8v*)(wsrc + (kel) + 8);                       \
    } while (0)

#define STORE_P(buf, set)                                                   \
    do {                                                                    \
        *(u8v*)(&As[buf][srow * 40 + scol])     = ar[set][0];               \
        *(u8v*)(&As[buf][srow * 40 + scol + 8]) = ar[set][1];               \
        *(u8v*)(&Bs[buf][srow * 40 + scol])     = wr[set][0];               \
        *(u8v*)(&Bs[buf][srow * 40 + scol + 8]) = wr[set][1];               \
    } while (0)

    LOAD_P(0, 0);
    LOAD_P(1, 32);
    STORE_P(0, 0);
    __syncthreads();

    #pragma unroll
    for (int ks = 0; ks < 8; ++ks) {
        const int cur = ks & 1;
        if (ks + 2 < 8) LOAD_P(cur, (ks + 2) * 32);
        s8v af[4], bf[4];
        #pragma unroll
        for (int i = 0; i < 4; ++i) {
            af[i] = *(const s8v*)(&As[cur][(wm + i * 16 + lq) * 40 + g * 8]);
            bf[i] = *(const s8v*)(&Bs[cur][(wn + i * 16 + lq) * 40 + g * 8]);
        }
        #pragma unroll
        for (int mt = 0; mt < 4; ++mt)
            #pragma unroll
            for (int nt = 0; nt < 4; ++nt)
                acc[mt][nt] = __builtin_amdgcn_mfma_f32_16x16x32_bf16(af[mt], bf[nt], acc[mt][nt], 0, 0, 0);
        if (ks < 7) STORE_P(cur ^ 1, (ks + 1) & 1);
        __syncthreads();
    }
#undef LOAD_P
#undef STORE_P

    #pragma unroll
    for (int nt = 0; nt < 4; ++nt) {
        const int n = bn + wn + nt * 16 + lq;
        const float bv = Bv[n];
        #pragma unroll
        for (int mt = 0; mt < 4; ++mt) {
            #pragma unroll
            for (int r = 0; r < 4; ++r) {
                const int mm = bm + wm + mt * 16 + g * 4 + r;
                Out[(size_t)mm * 256 + n] = acc[mt][nt][r] + bv;
            }
        }
    }
}

extern "C" void kernel_launch(void* const* d_in, const int* in_sizes, int n_in,
                              void* d_out, int out_size, void* d_ws, size_t ws_size,
                              hipStream_t stream) {
    const float* x      = (const float*)d_in[0];
    const float* qkv_w  = (const float*)d_in[1];
    const float* qkv_b  = (const float*)d_in[2];
    const float* proj_w = (const float*)d_in[3];
    const float* proj_b = (const float*)d_in[4];
    const float* rel    = (const float*)d_in[5];
    float* out = (float*)d_out;

    uint16_t* ws = (uint16_t*)d_ws;
    const size_t QE = (size_t)NB * NH * NS * ND;          // 8,388,608 elems
    uint16_t* Qb   = ws;                                  // 16 MiB
    uint16_t* Kb   = Qb + QE;                             // 16 MiB
    uint16_t* Vb   = Kb + QE;                             // 16 MiB
    uint16_t* Rb   = Vb + QE;                             // 16 MiB: AO
    uint16_t* REL2 = Rb + QE;                             // 8 x 20480 bf16 (320 KiB)
    uint16_t* Wqb  = REL2 + 163840;                       // 768x256 bf16 (384 KiB)
    uint16_t* Wpb  = Wqb + 196608;                        // 256x256 bf16 (128 KiB)

    setup_kern<<<768, 256, 0, stream>>>(rel, qkv_w, proj_w, REL2, Wqb, Wpb);
    qkv_gemm<<<dim3(512, 6), 256, 0, stream>>>(x, Wqb, qkv_b, Qb, Kb, Vb);
    attn_kern<<<2048, 512, 0, stream>>>(Qb, Kb, Vb, REL2, Rb);
    proj_gemm<<<dim3(256, 2), 256, 0, stream>>>(Rb, Wpb, proj_b, out);
}